// Round 4
// baseline (753.294 us; speedup 1.0000x reference)
//
#include <hip/hip_runtime.h>
#include <hip/hip_bf16.h>

typedef unsigned short u16;
typedef unsigned int   u32;
typedef __attribute__((ext_vector_type(8))) short bf16x8;
typedef __attribute__((ext_vector_type(4))) float f32x4;

#define GRID_MLP 768       // 3 blocks/CU * 256 CUs
#define NBATCH   8192

__device__ __forceinline__ u32 pack2bf(float a, float b) {
    __hip_bfloat162 h = __float22bfloat162_rn(make_float2(a, b));  // v_cvt_pk_bf16_f32
    return *reinterpret_cast<u32*>(&h);
}

__device__ __forceinline__ u16 f2bf(float x) {
    u32 u = __float_as_uint(x);
    u32 r = u + 0x7FFFu + ((u >> 16) & 1u);
    return (u16)(r >> 16);
}

// d_ws: w1t = bf16 W1^T [c=256][d=128] (d contig), w2t = bf16 W2^T [e=256][c=256] (c contig)
__global__ __launch_bounds__(256) void prep_weights(
    const float* __restrict__ W1, const float* __restrict__ W2,
    u16* __restrict__ w1t, u16* __restrict__ w2t)
{
    int tid = blockIdx.x * 256 + threadIdx.x;
    if (tid < 128 * 256) {
        int c = tid >> 7, d = tid & 127;
        w1t[tid] = f2bf(W1[d * 256 + c]);
    } else {
        int t2 = tid - 128 * 256;
        if (t2 < 256 * 256) {
            int e = t2 >> 8, c = t2 & 255;
            w2t[t2] = f2bf(W2[c * 256 + e]);
        }
    }
}

// Persistent blocks, 2 barriers/iter software pipeline:
//   iter(b): issue X-loads(b+GRID) | L1(xt=b) | B1 | out(b-GRID) from partl |
//            ep1->h1 | cvt+xt-write(b+GRID) | B2 | L2(h1)+L3->partl
// Hazards: xt R(L1)->W(step5) spans B1; xt W->R spans B2; h1 R(prev L2)->W(ep1)
// spans B1 (program order: prev L2 before this L1); h1 W->R spans B2;
// partl W(L3)->R(next out) spans next B1; partl R->W spans B2.
__global__ __launch_bounds__(256, 3) void fused_mlp(
    const float* __restrict__ X,
    const float* __restrict__ b1, const float* __restrict__ b2,
    const float* __restrict__ W3, const float* __restrict__ b3,
    const u16* __restrict__ w1t, const u16* __restrict__ w2t,
    float* __restrict__ out)
{
    __shared__ u16   xt[64 * 128];    // bf16 XT[n][d], 16B-chunk XOR-swizzled by (n&15)
    __shared__ u16   h1s[64 * 256];   // bf16 h1[n][c], same swizzle
    __shared__ float partl[4][64];    // per-wave logit partials (deferred reduce)

    const int tid = threadIdx.x;
    const int w   = tid >> 6;
    const int l   = tid & 63;
    const int lc  = l & 15;
    const int lk  = l >> 4;

    // loop-invariant hoists
    float b2v[4], w3v[4];
    #pragma unroll
    for (int nt = 0; nt < 4; ++nt) {
        const int e = 64 * w + 16 * nt + lc;
        b2v[nt] = b2[e];
        w3v[nt] = W3[e];
    }
    const float b3v = b3[0];

    // ---------- prologue: stage batch b0 straight into xt ----------
    int b = blockIdx.x;
    {
        const float* Xb = X + (size_t)b * 8192;
        #pragma unroll
        for (int it = 0; it < 4; ++it) {
            const int dc = w + 4 * it, d0 = dc << 3;
            float v[8];
            #pragma unroll
            for (int j = 0; j < 8; ++j) v[j] = Xb[(d0 + j) * 64 + l];
            u32 pk[4];
            #pragma unroll
            for (int j = 0; j < 4; ++j) pk[j] = pack2bf(v[2 * j], v[2 * j + 1]);
            *(uint4*)(xt + l * 128 + ((dc ^ lc) << 3)) = make_uint4(pk[0], pk[1], pk[2], pk[3]);
        }
    }
    __syncthreads();

    int prev = -1;
    for (; b < NBATCH; b += GRID_MLP) {
        const int  bn       = b + GRID_MLP;
        const bool has_next = bn < NBATCH;

        // ---- 1) issue next-batch X loads (consumed in step 5; HBM latency hidden under L1+ep1) ----
        float stg[4][8];
        if (has_next) {
            const float* Xb = X + (size_t)bn * 8192;
            #pragma unroll
            for (int it = 0; it < 4; ++it) {
                const int d0 = (w + 4 * it) << 3;
                #pragma unroll
                for (int j = 0; j < 8; ++j) stg[it][j] = Xb[(d0 + j) * 64 + l];
            }
        }

        // ---- 2) layer 1: D1[c][n] = sum_d W1T[c][d] * XT[n][d] ----
        f32x4 acc[4][4];
        #pragma unroll
        for (int mt = 0; mt < 4; ++mt)
            #pragma unroll
            for (int nt = 0; nt < 4; ++nt) acc[mt][nt] = (f32x4){0.f, 0.f, 0.f, 0.f};

        #pragma unroll
        for (int ks = 0; ks < 4; ++ks) {
            bf16x8 afr[4], bfr[4];
            #pragma unroll
            for (int mt = 0; mt < 4; ++mt)
                afr[mt] = *(const bf16x8*)(w1t + (64 * w + 16 * mt + lc) * 128 + 32 * ks + 8 * lk);
            #pragma unroll
            for (int nt = 0; nt < 4; ++nt) {
                const int n = 16 * nt + lc;
                bfr[nt] = *(const bf16x8*)(xt + n * 128 + (((4 * ks + lk) ^ lc) << 3));
            }
            #pragma unroll
            for (int mt = 0; mt < 4; ++mt)
                #pragma unroll
                for (int nt = 0; nt < 4; ++nt)
                    acc[mt][nt] = __builtin_amdgcn_mfma_f32_16x16x32_bf16(afr[mt], bfr[nt], acc[mt][nt], 0, 0, 0);
        }
        __syncthreads();                                   // B1

        // ---- 3) write out logits of previous batch (partl from its L3) ----
        if (prev >= 0) {
            if (tid < 64) {
                float s = partl[0][tid] + partl[1][tid] + partl[2][tid] + partl[3][tid] + b3v;
                out[(size_t)prev * 65 + 1 + tid] = s;
            } else if (tid == 64) {
                out[(size_t)prev * 65] = 0.f;
            }
        }

        // ---- 4) epilogue 1: +b1, relu, bf16 -> h1s ----
        #pragma unroll
        for (int mt = 0; mt < 4; ++mt) {
            const int c0 = 64 * w + 16 * mt + 4 * lk;
            const float4 bv = *(const float4*)(b1 + c0);
            #pragma unroll
            for (int nt = 0; nt < 4; ++nt) {
                const int n = 16 * nt + lc;
                float x0 = fmaxf(acc[mt][nt][0] + bv.x, 0.f);
                float x1 = fmaxf(acc[mt][nt][1] + bv.y, 0.f);
                float x2 = fmaxf(acc[mt][nt][2] + bv.z, 0.f);
                float x3 = fmaxf(acc[mt][nt][3] + bv.w, 0.f);
                u32 lo = pack2bf(x0, x1);
                u32 hi = pack2bf(x2, x3);
                const int chunk = (c0 >> 3) ^ lc;
                *(uint2*)(h1s + n * 256 + (chunk << 3) + (c0 & 7)) = make_uint2(lo, hi);
            }
        }

        // ---- 5) cvt staged X -> xt (write-late; all xt readers passed B1) ----
        if (has_next) {
            #pragma unroll
            for (int it = 0; it < 4; ++it) {
                const int dc = w + 4 * it;
                u32 pk[4];
                #pragma unroll
                for (int j = 0; j < 4; ++j) pk[j] = pack2bf(stg[it][2 * j], stg[it][2 * j + 1]);
                *(uint4*)(xt + l * 128 + ((dc ^ lc) << 3)) = make_uint4(pk[0], pk[1], pk[2], pk[3]);
            }
        }
        __syncthreads();                                   // B2

        // ---- 6) layer 2 + layer 3 ----
        f32x4 acc2[4][4];
        #pragma unroll
        for (int mt = 0; mt < 4; ++mt)
            #pragma unroll
            for (int nt = 0; nt < 4; ++nt) acc2[mt][nt] = (f32x4){0.f, 0.f, 0.f, 0.f};

        #pragma unroll
        for (int ks = 0; ks < 8; ++ks) {
            bf16x8 afr[4], bfr[4];
            #pragma unroll
            for (int nt = 0; nt < 4; ++nt)
                bfr[nt] = *(const bf16x8*)(w2t + (64 * w + 16 * nt + lc) * 256 + 32 * ks + 8 * lk);
            #pragma unroll
            for (int mt = 0; mt < 4; ++mt) {
                const int n = 16 * mt + lc;
                afr[mt] = *(const bf16x8*)(h1s + n * 256 + (((4 * ks + lk) ^ lc) << 3));
            }
            #pragma unroll
            for (int mt = 0; mt < 4; ++mt)
                #pragma unroll
                for (int nt = 0; nt < 4; ++nt)
                    acc2[mt][nt] = __builtin_amdgcn_mfma_f32_16x16x32_bf16(afr[mt], bfr[nt], acc2[mt][nt], 0, 0, 0);
        }

        #pragma unroll
        for (int mt = 0; mt < 4; ++mt) {
            #pragma unroll
            for (int j = 0; j < 4; ++j) {                 // D2 row n = 16mt + 4lk + j
                float s = 0.f;
                #pragma unroll
                for (int nt = 0; nt < 4; ++nt)
                    s += fmaxf(acc2[mt][nt][j] + b2v[nt], 0.f) * w3v[nt];
                s += __shfl_xor(s, 1);
                s += __shfl_xor(s, 2);
                s += __shfl_xor(s, 4);
                s += __shfl_xor(s, 8);
                if (lc == 0) partl[w][16 * mt + 4 * lk + j] = s;
            }
        }
        prev = b;
    }

    // ---- drain: final batch's output ----
    __syncthreads();
    if (tid < 64) {
        float s = partl[0][tid] + partl[1][tid] + partl[2][tid] + partl[3][tid] + b3v;
        out[(size_t)prev * 65 + 1 + tid] = s;
    } else if (tid == 64) {
        out[(size_t)prev * 65] = 0.f;
    }
}

extern "C" void kernel_launch(void* const* d_in, const int* in_sizes, int n_in,
                              void* d_out, int out_size, void* d_ws, size_t ws_size,
                              hipStream_t stream) {
    const float* X  = (const float*)d_in[0];
    const float* W1 = (const float*)d_in[1];
    const float* b1 = (const float*)d_in[2];
    const float* W2 = (const float*)d_in[3];
    const float* b2 = (const float*)d_in[4];
    const float* W3 = (const float*)d_in[5];
    const float* b3 = (const float*)d_in[6];
    float* out = (float*)d_out;

    u16* w1t = (u16*)d_ws;            // 256*128 bf16 = 64 KB
    u16* w2t = w1t + 256 * 128;       // 256*256 bf16 = 128 KB

    prep_weights<<<384, 256, 0, stream>>>(W1, W2, w1t, w2t);
    fused_mlp<<<GRID_MLP, 256, 0, stream>>>(X, b1, b2, W3, b3, w1t, w2t, out);
}

// Round 5
// 299.984 us; speedup vs baseline: 2.5111x; 2.5111x over previous
//
#include <hip/hip_runtime.h>
#include <hip/hip_bf16.h>

typedef unsigned short u16;
typedef unsigned int   u32;
typedef __attribute__((ext_vector_type(8))) short bf16x8;
typedef __attribute__((ext_vector_type(4))) float f32x4;

#define NB 8192

__device__ __forceinline__ u32 pack2bf(float a, float b) {
    __hip_bfloat162 h = __float22bfloat162_rn(make_float2(a, b));  // v_cvt_pk_bf16_f32
    return *reinterpret_cast<u32*>(&h);
}

__device__ __forceinline__ u16 f2bf(float x) {
    u32 u = __float_as_uint(x);
    u32 r = u + 0x7FFFu + ((u >> 16) & 1u);
    return (u16)(r >> 16);
}

// d_ws: w1t bf16 W1^T [c=256][d=128] (d contig), w2t bf16 W2^T [e=256][c=256] (c contig),
//       h1 bf16 tiled: chunk(b,w,mt,nt) of 512B; elem = chunk*256 + lc*16 + lk*4
__global__ __launch_bounds__(256) void prep_weights(
    const float* __restrict__ W1, const float* __restrict__ W2,
    u16* __restrict__ w1t, u16* __restrict__ w2t)
{
    int tid = blockIdx.x * 256 + threadIdx.x;
    if (tid < 128 * 256) {
        int c = tid >> 7, d = tid & 127;
        w1t[tid] = f2bf(W1[d * 256 + c]);
    } else {
        int t2 = tid - 128 * 256;
        if (t2 < 256 * 256) {
            int e = t2 >> 8, c = t2 & 255;
            w2t[t2] = f2bf(W2[c * 256 + e]);
        }
    }
}

// ============ K1: h1 = relu(W1^T · X[b] + b1), tiled bf16 to global ============
// One block = one batch. Stage X^T -> LDS (16KB), L1 MFMAs (swapped: D1[c][n]),
// epilogue stores dense 512B chunks. One barrier total.
__global__ __launch_bounds__(256, 4) void k1_l1(
    const float* __restrict__ X, const float* __restrict__ b1,
    const u16* __restrict__ w1t, u16* __restrict__ h1)
{
    __shared__ u16 xt[64 * 128];      // bf16 XT[n][d], 16B-chunk XOR-swizzled by (n&15)

    const int tid = threadIdx.x;
    const int w   = tid >> 6;
    const int l   = tid & 63;
    const int lc  = l & 15;
    const int lk  = l >> 4;
    const int b   = blockIdx.x;
    const float* Xb = X + (size_t)b * 8192;

    // stage: X[d][n] -> XT[n][d] bf16 (transpose via strided coalesced loads)
    #pragma unroll
    for (int it = 0; it < 4; ++it) {
        const int dc = w + 4 * it, d0 = dc << 3;
        float v[8];
        #pragma unroll
        for (int j = 0; j < 8; ++j) v[j] = Xb[(d0 + j) * 64 + l];
        u32 pk[4];
        #pragma unroll
        for (int j = 0; j < 4; ++j) pk[j] = pack2bf(v[2 * j], v[2 * j + 1]);
        *(uint4*)(xt + l * 128 + ((dc ^ lc) << 3)) = make_uint4(pk[0], pk[1], pk[2], pk[3]);
    }
    __syncthreads();

    // L1: D1[c][n] = sum_d W1T[c][d] * XT[n][d]
    f32x4 acc[4][4];
    #pragma unroll
    for (int mt = 0; mt < 4; ++mt)
        #pragma unroll
        for (int nt = 0; nt < 4; ++nt) acc[mt][nt] = (f32x4){0.f, 0.f, 0.f, 0.f};

    #pragma unroll
    for (int ks = 0; ks < 4; ++ks) {
        bf16x8 afr[4], bfr[4];
        #pragma unroll
        for (int mt = 0; mt < 4; ++mt)
            afr[mt] = *(const bf16x8*)(w1t + (64 * w + 16 * mt + lc) * 128 + 32 * ks + 8 * lk);
        #pragma unroll
        for (int nt = 0; nt < 4; ++nt)
            bfr[nt] = *(const bf16x8*)(xt + (16 * nt + lc) * 128 + (((4 * ks + lk) ^ lc) << 3));
        #pragma unroll
        for (int mt = 0; mt < 4; ++mt)
            #pragma unroll
            for (int nt = 0; nt < 4; ++nt)
                acc[mt][nt] = __builtin_amdgcn_mfma_f32_16x16x32_bf16(afr[mt], bfr[nt], acc[mt][nt], 0, 0, 0);
    }

    // epilogue: +b1, relu, bf16, store tiled chunks (dense 512B per wave-instr)
    #pragma unroll
    for (int mt = 0; mt < 4; ++mt) {
        const int c0 = 64 * w + 16 * mt + 4 * lk;       // c = c0 + reg
        const float4 bv = *(const float4*)(b1 + c0);
        #pragma unroll
        for (int nt = 0; nt < 4; ++nt) {
            float x0 = fmaxf(acc[mt][nt][0] + bv.x, 0.f);
            float x1 = fmaxf(acc[mt][nt][1] + bv.y, 0.f);
            float x2 = fmaxf(acc[mt][nt][2] + bv.z, 0.f);
            float x3 = fmaxf(acc[mt][nt][3] + bv.w, 0.f);
            const int chunk = ((b * 4 + w) * 4 + mt) * 4 + nt;   // row n = 16nt+lc
            *(uint2*)(h1 + chunk * 256 + lc * 16 + lk * 4) =
                make_uint2(pack2bf(x0, x1), pack2bf(x2, x3));
        }
    }
}

// ============ K2: logits = relu(h1·W2 + b2)·W3 + b3 ============
// One block = one batch; wave w owns e-slice [64w,64w+64). No LDS for data,
// no barriers until the tiny final cross-wave reduce. A-frags stream h1 tiles
// straight from global (16B/lane, k-contig by layout construction).
__global__ __launch_bounds__(256, 4) void k2_l23(
    const u16* __restrict__ h1, const u16* __restrict__ w2t,
    const float* __restrict__ b2, const float* __restrict__ W3,
    const float* __restrict__ b3, float* __restrict__ out)
{
    __shared__ float partl[4][64];

    const int tid = threadIdx.x;
    const int w   = tid >> 6;
    const int l   = tid & 63;
    const int lc  = l & 15;
    const int lk  = l >> 4;
    const int b   = blockIdx.x;

    float b2v[4], w3v[4];
    #pragma unroll
    for (int et = 0; et < 4; ++et) {
        const int e = 64 * w + 16 * et + lc;
        b2v[et] = b2[e];
        w3v[et] = W3[e];
    }
    const float b3v = b3[0];

    f32x4 acc[4][4];   // [rt][et]
    #pragma unroll
    for (int rt = 0; rt < 4; ++rt)
        #pragma unroll
        for (int et = 0; et < 4; ++et) acc[rt][et] = (f32x4){0.f, 0.f, 0.f, 0.f};

    // per-lane invariant part of the h1 tile address (elements)
    const int a0 = b * 16384 + lc * 16 + (lk & 1) * 8;

    #pragma unroll
    for (int ks = 0; ks < 8; ++ks) {
        const int wsrc = (4 * ks + lk) >> 3;            // uniform per ks
        const int msrc = (2 * ks + (lk >> 1)) & 3;
        bf16x8 afr[4], bfr[4];
        #pragma unroll
        for (int rt = 0; rt < 4; ++rt)
            afr[rt] = *(const bf16x8*)(h1 + a0 + wsrc * 4096 + msrc * 1024 + rt * 256);
        #pragma unroll
        for (int et = 0; et < 4; ++et)
            bfr[et] = *(const bf16x8*)(w2t + (64 * w + 16 * et + lc) * 256 + 32 * ks + 8 * lk);
        #pragma unroll
        for (int rt = 0; rt < 4; ++rt)
            #pragma unroll
            for (int et = 0; et < 4; ++et)
                acc[rt][et] = __builtin_amdgcn_mfma_f32_16x16x32_bf16(afr[rt], bfr[et], acc[rt][et], 0, 0, 0);
    }

    // L3: +b2, relu, dot W3, reduce over e. Lane holds rows n=16rt+4lk+j, e=64w+16et+lc.
    #pragma unroll
    for (int rt = 0; rt < 4; ++rt) {
        #pragma unroll
        for (int j = 0; j < 4; ++j) {
            float s = 0.f;
            #pragma unroll
            for (int et = 0; et < 4; ++et)
                s += fmaxf(acc[rt][et][j] + b2v[et], 0.f) * w3v[et];
            s += __shfl_xor(s, 1);
            s += __shfl_xor(s, 2);
            s += __shfl_xor(s, 4);
            s += __shfl_xor(s, 8);
            if (lc == 0) partl[w][16 * rt + 4 * lk + j] = s;
        }
    }
    __syncthreads();

    if (tid < 64) {
        float s = partl[0][tid] + partl[1][tid] + partl[2][tid] + partl[3][tid] + b3v;
        out[(size_t)b * 65 + 1 + tid] = s;
    } else if (tid == 64) {
        out[(size_t)b * 65] = 0.f;
    }
}

// ============ Fallback: R3 fused kernel (used if ws too small for h1) ============
__global__ __launch_bounds__(256, 4) void fused_mlp(
    const float* __restrict__ X,
    const float* __restrict__ b1, const float* __restrict__ b2,
    const float* __restrict__ W3, const float* __restrict__ b3,
    const u16* __restrict__ w1t, const u16* __restrict__ w2t,
    float* __restrict__ out)
{
    __shared__ u16 smem[64 * 256];
    u16* xt  = smem;
    u16* h1s = smem;
    float* partl = (float*)smem;

    const int tid = threadIdx.x;
    const int w   = tid >> 6;
    const int l   = tid & 63;
    const int lc  = l & 15;
    const int lk  = l >> 4;
    const int b   = blockIdx.x;
    const float* Xb = X + (size_t)b * 8192;

    #pragma unroll
    for (int it = 0; it < 4; ++it) {
        const int dc = w + 4 * it, d0 = dc << 3;
        float v[8];
        #pragma unroll
        for (int j = 0; j < 8; ++j) v[j] = Xb[(d0 + j) * 64 + l];
        u32 pk[4];
        #pragma unroll
        for (int j = 0; j < 4; ++j) pk[j] = pack2bf(v[2 * j], v[2 * j + 1]);
        *(uint4*)(xt + l * 128 + ((dc ^ lc) << 3)) = make_uint4(pk[0], pk[1], pk[2], pk[3]);
    }
    __syncthreads();

    f32x4 acc[4][4];
    #pragma unroll
    for (int mt = 0; mt < 4; ++mt)
        #pragma unroll
        for (int nt = 0; nt < 4; ++nt) acc[mt][nt] = (f32x4){0.f, 0.f, 0.f, 0.f};
    #pragma unroll
    for (int ks = 0; ks < 4; ++ks) {
        bf16x8 afr[4], bfr[4];
        #pragma unroll
        for (int mt = 0; mt < 4; ++mt)
            afr[mt] = *(const bf16x8*)(w1t + (64 * w + 16 * mt + lc) * 128 + 32 * ks + 8 * lk);
        #pragma unroll
        for (int nt = 0; nt < 4; ++nt)
            bfr[nt] = *(const bf16x8*)(xt + (16 * nt + lc) * 128 + (((4 * ks + lk) ^ lc) << 3));
        #pragma unroll
        for (int mt = 0; mt < 4; ++mt)
            #pragma unroll
            for (int nt = 0; nt < 4; ++nt)
                acc[mt][nt] = __builtin_amdgcn_mfma_f32_16x16x32_bf16(afr[mt], bfr[nt], acc[mt][nt], 0, 0, 0);
    }
    __syncthreads();

    #pragma unroll
    for (int mt = 0; mt < 4; ++mt) {
        const int c0 = 64 * w + 16 * mt + 4 * lk;
        const float4 bv = *(const float4*)(b1 + c0);
        #pragma unroll
        for (int nt = 0; nt < 4; ++nt) {
            const int n = 16 * nt + lc;
            float x0 = fmaxf(acc[mt][nt][0] + bv.x, 0.f);
            float x1 = fmaxf(acc[mt][nt][1] + bv.y, 0.f);
            float x2 = fmaxf(acc[mt][nt][2] + bv.z, 0.f);
            float x3 = fmaxf(acc[mt][nt][3] + bv.w, 0.f);
            const int chunk = (c0 >> 3) ^ lc;
            *(uint2*)(h1s + n * 256 + (chunk << 3) + (c0 & 7)) =
                make_uint2(pack2bf(x0, x1), pack2bf(x2, x3));
        }
    }
    __syncthreads();

    f32x4 acc2[4][4];
    #pragma unroll
    for (int mt = 0; mt < 4; ++mt)
        #pragma unroll
        for (int nt = 0; nt < 4; ++nt) acc2[mt][nt] = (f32x4){0.f, 0.f, 0.f, 0.f};
    #pragma unroll
    for (int ks = 0; ks < 8; ++ks) {
        bf16x8 afr[4], bfr[4];
        #pragma unroll
        for (int nt = 0; nt < 4; ++nt)
            bfr[nt] = *(const bf16x8*)(w2t + (64 * w + 16 * nt + lc) * 256 + 32 * ks + 8 * lk);
        #pragma unroll
        for (int mt = 0; mt < 4; ++mt)
            afr[mt] = *(const bf16x8*)(h1s + (16 * mt + lc) * 256 + (((4 * ks + lk) ^ lc) << 3));
        #pragma unroll
        for (int mt = 0; mt < 4; ++mt)
            #pragma unroll
            for (int nt = 0; nt < 4; ++nt)
                acc2[mt][nt] = __builtin_amdgcn_mfma_f32_16x16x32_bf16(afr[mt], bfr[nt], acc2[mt][nt], 0, 0, 0);
    }
    __syncthreads();

    float b2v[4], w3v[4];
    #pragma unroll
    for (int nt = 0; nt < 4; ++nt) {
        const int e = 64 * w + 16 * nt + lc;
        b2v[nt] = b2[e];
        w3v[nt] = W3[e];
    }
    #pragma unroll
    for (int mt = 0; mt < 4; ++mt) {
        #pragma unroll
        for (int j = 0; j < 4; ++j) {
            float s = 0.f;
            #pragma unroll
            for (int nt = 0; nt < 4; ++nt)
                s += fmaxf(acc2[mt][nt][j] + b2v[nt], 0.f) * w3v[nt];
            s += __shfl_xor(s, 1);
            s += __shfl_xor(s, 2);
            s += __shfl_xor(s, 4);
            s += __shfl_xor(s, 8);
            if (lc == 0) partl[w * 64 + 16 * mt + 4 * lk + j] = s;
        }
    }
    __syncthreads();

    if (tid < 64) {
        float s = partl[0 * 64 + tid] + partl[1 * 64 + tid] + partl[2 * 64 + tid] + partl[3 * 64 + tid] + b3[0];
        out[(size_t)b * 65 + 1 + tid] = s;
    } else if (tid == 64) {
        out[(size_t)b * 65] = 0.f;
    }
}

extern "C" void kernel_launch(void* const* d_in, const int* in_sizes, int n_in,
                              void* d_out, int out_size, void* d_ws, size_t ws_size,
                              hipStream_t stream) {
    const float* X  = (const float*)d_in[0];
    const float* W1 = (const float*)d_in[1];
    const float* b1 = (const float*)d_in[2];
    const float* W2 = (const float*)d_in[3];
    const float* b2 = (const float*)d_in[4];
    const float* W3 = (const float*)d_in[5];
    const float* b3 = (const float*)d_in[6];
    float* out = (float*)d_out;

    u16* w1t = (u16*)d_ws;             // 64 KB
    u16* w2t = w1t + 256 * 128;        // 128 KB
    u16* h1  = w2t + 256 * 256;        // 268.4 MB (split path)

    const size_t need = (size_t)(256 * 128 + 256 * 256) * 2 + (size_t)NB * 64 * 256 * 2;

    prep_weights<<<384, 256, 0, stream>>>(W1, W2, w1t, w2t);
    if (ws_size >= need) {
        k1_l1 <<<NB, 256, 0, stream>>>(X, b1, w1t, h1);
        k2_l23<<<NB, 256, 0, stream>>>(h1, w2t, b2, W3, b3, out);
    } else {
        fused_mlp<<<NB, 256, 0, stream>>>(X, b1, b2, W3, b3, w1t, w2t, out);
    }
}

// Round 6
// 201.921 us; speedup vs baseline: 3.7306x; 1.4856x over previous
//
#include <hip/hip_runtime.h>
#include <hip/hip_bf16.h>

typedef unsigned short u16;
typedef unsigned int   u32;
typedef __attribute__((ext_vector_type(8))) short bf16x8;
typedef __attribute__((ext_vector_type(4))) float f32x4;

#define NB 8192

__device__ __forceinline__ u32 pack2bf(float a, float b) {
    __hip_bfloat162 h = __float22bfloat162_rn(make_float2(a, b));  // v_cvt_pk_bf16_f32
    return *reinterpret_cast<u32*>(&h);
}

__device__ __forceinline__ u16 f2bf(float x) {
    u32 u = __float_as_uint(x);
    u32 r = u + 0x7FFFu + ((u >> 16) & 1u);
    return (u16)(r >> 16);
}

// d_ws: w1t bf16 W1^T [c=256][d=128] (d contig), w2t bf16 W2^T [e=256][c=256] (c contig)
__global__ __launch_bounds__(256) void prep_weights(
    const float* __restrict__ W1, const float* __restrict__ W2,
    u16* __restrict__ w1t, u16* __restrict__ w2t)
{
    int tid = blockIdx.x * 256 + threadIdx.x;
    if (tid < 128 * 256) {
        int c = tid >> 7, d = tid & 127;
        w1t[tid] = f2bf(W1[d * 256 + c]);
    } else {
        int t2 = tid - 128 * 256;
        if (t2 < 256 * 256) {
            int e = t2 >> 8, c = t2 & 255;
            w2t[t2] = f2bf(W2[c * 256 + e]);
        }
    }
}

// One block = one batch b (64 nodes), 4 waves. 32KB arena aliases:
//   xs  : X[b] fp32 [d=128][n=64], column-swizzled: LDS word d*64+m holds X[d][m^p(d)],
//         p(d) = 16*((d>>3)&1). Staged via global_load_lds (8 instr/wave, no VGPR trip).
//   h1s : bf16 h1[n][c], R3's 16B-chunk XOR swizzle. Same 32KB, disjoint lifetime.
// partl separate 1KB. 33.75KB/block -> 4 blocks/CU. 4 barriers/block.
__global__ __launch_bounds__(256, 4) void fused_mlp(
    const float* __restrict__ X,
    const float* __restrict__ b1, const float* __restrict__ b2,
    const float* __restrict__ W3, const float* __restrict__ b3,
    const u16* __restrict__ w1t, const u16* __restrict__ w2t,
    float* __restrict__ out)
{
    __shared__ __align__(16) float arena_f[64 * 128];   // 32 KB
    float* xs = arena_f;
    u16*   h1s = (u16*)arena_f;
    __shared__ float partl[4][64];

    const int tid = threadIdx.x;
    const int w   = tid >> 6;
    const int l   = tid & 63;
    const int lc  = l & 15;
    const int lk  = l >> 4;
    const int b   = blockIdx.x;
    const float* Xb = X + (size_t)b * 8192;

    // ---------- phase 0: stage X[b] fp32 -> LDS via global_load_lds (pre-swizzled source) ----------
    // iteration i: wave w fills LDS bytes [i*4096 + w*1024 + lane*16).
    {
        const int dl = w * 4 + (l >> 4);          // d within the i-block, +16 per i
        const int m0 = (l & 15) * 4;              // word within row (before swizzle)
        #pragma unroll
        for (int i = 0; i < 8; ++i) {
            const int d = i * 16 + dl;
            const float* src = Xb + d * 64 + (m0 ^ (((d >> 3) & 1) << 4));
            __builtin_amdgcn_global_load_lds(
                (const __attribute__((address_space(1))) void*)src,
                (__attribute__((address_space(3))) void*)(xs + i * 1024 + w * 256 + (l & 63) * 4),
                16, 0, 0);
        }
    }

    // hoist ks=0 A-frag loads (w1t, no LDS dep) above the barrier
    bf16x8 afrN[4];
    #pragma unroll
    for (int mt = 0; mt < 4; ++mt)
        afrN[mt] = *(const bf16x8*)(w1t + (64 * w + 16 * mt + lc) * 128 + 8 * lk);
    __syncthreads();                               // B0: drains vmcnt -> xs valid

    // ---------- layer 1: D1[c][n] = sum_d W1T[c][d] * X[d][n] ----------
    f32x4 acc[4][4];
    #pragma unroll
    for (int mt = 0; mt < 4; ++mt)
        #pragma unroll
        for (int nt = 0; nt < 4; ++nt) acc[mt][nt] = (f32x4){0.f, 0.f, 0.f, 0.f};

    const int px = (lk & 1) << 4;                  // read-side column swizzle
    #pragma unroll
    for (int ks = 0; ks < 4; ++ks) {
        bf16x8 afr[4], bfr[4];
        #pragma unroll
        for (int mt = 0; mt < 4; ++mt) afr[mt] = afrN[mt];
        if (ks < 3) {
            #pragma unroll
            for (int mt = 0; mt < 4; ++mt)
                afrN[mt] = *(const bf16x8*)(w1t + (64 * w + 16 * mt + lc) * 128 + 32 * (ks + 1) + 8 * lk);
        }
        #pragma unroll
        for (int nt = 0; nt < 4; ++nt) {
            const int col = (16 * nt + lc) ^ px;
            const int rb  = (32 * ks + 8 * lk) * 64 + col;
            float xv[8];
            #pragma unroll
            for (int j = 0; j < 8; ++j) xv[j] = xs[rb + j * 64];   // ds_read_b32, 2-way banks
            union { bf16x8 v; u32 d[4]; } fr;
            #pragma unroll
            for (int j = 0; j < 4; ++j) fr.d[j] = pack2bf(xv[2 * j], xv[2 * j + 1]);
            bfr[nt] = fr.v;
        }
        #pragma unroll
        for (int mt = 0; mt < 4; ++mt)
            #pragma unroll
            for (int nt = 0; nt < 4; ++nt)
                acc[mt][nt] = __builtin_amdgcn_mfma_f32_16x16x32_bf16(afr[mt], bfr[nt], acc[mt][nt], 0, 0, 0);
    }
    __syncthreads();                               // B1: all waves done reading xs

    // ---------- epilogue 1: +b1, relu, bf16 -> h1s (arena) ----------
    #pragma unroll
    for (int mt = 0; mt < 4; ++mt) {
        const int c0 = 64 * w + 16 * mt + 4 * lk;
        const float4 bv = *(const float4*)(b1 + c0);
        #pragma unroll
        for (int nt = 0; nt < 4; ++nt) {
            const int n = 16 * nt + lc;
            float x0 = fmaxf(acc[mt][nt][0] + bv.x, 0.f);
            float x1 = fmaxf(acc[mt][nt][1] + bv.y, 0.f);
            float x2 = fmaxf(acc[mt][nt][2] + bv.z, 0.f);
            float x3 = fmaxf(acc[mt][nt][3] + bv.w, 0.f);
            const int chunk = (c0 >> 3) ^ lc;
            *(uint2*)(h1s + n * 256 + (chunk << 3) + (c0 & 7)) =
                make_uint2(pack2bf(x0, x1), pack2bf(x2, x3));
        }
    }

    // hoist ks=0 B-frag loads (w2t) above the barrier
    bf16x8 bfrN[4];
    #pragma unroll
    for (int nt = 0; nt < 4; ++nt)
        bfrN[nt] = *(const bf16x8*)(w2t + (64 * w + 16 * nt + lc) * 256 + 8 * lk);
    __syncthreads();                               // B2: h1s visible

    // ---------- layer 2: D2[n][e] = sum_c h1[n][c] * W2T[e][c] ----------
    f32x4 acc2[4][4];
    #pragma unroll
    for (int mt = 0; mt < 4; ++mt)
        #pragma unroll
        for (int nt = 0; nt < 4; ++nt) acc2[mt][nt] = (f32x4){0.f, 0.f, 0.f, 0.f};

    #pragma unroll
    for (int ks = 0; ks < 8; ++ks) {
        bf16x8 afr[4], bfr[4];
        #pragma unroll
        for (int nt = 0; nt < 4; ++nt) bfr[nt] = bfrN[nt];
        if (ks < 7) {
            #pragma unroll
            for (int nt = 0; nt < 4; ++nt)
                bfrN[nt] = *(const bf16x8*)(w2t + (64 * w + 16 * nt + lc) * 256 + 32 * (ks + 1) + 8 * lk);
        }
        #pragma unroll
        for (int mt = 0; mt < 4; ++mt)
            afr[mt] = *(const bf16x8*)(h1s + (16 * mt + lc) * 256 + (((4 * ks + lk) ^ lc) << 3));
        #pragma unroll
        for (int mt = 0; mt < 4; ++mt)
            #pragma unroll
            for (int nt = 0; nt < 4; ++nt)
                acc2[mt][nt] = __builtin_amdgcn_mfma_f32_16x16x32_bf16(afr[mt], bfr[nt], acc2[mt][nt], 0, 0, 0);
    }

    // ---------- layer 3: +b2, relu, dot W3, reduce over e ----------
    float b2v[4], w3v[4];
    #pragma unroll
    for (int nt = 0; nt < 4; ++nt) {
        const int e = 64 * w + 16 * nt + lc;
        b2v[nt] = b2[e];
        w3v[nt] = W3[e];
    }
    #pragma unroll
    for (int mt = 0; mt < 4; ++mt) {
        #pragma unroll
        for (int j = 0; j < 4; ++j) {              // D2 row n = 16mt + 4lk + j
            float s = 0.f;
            #pragma unroll
            for (int nt = 0; nt < 4; ++nt)
                s += fmaxf(acc2[mt][nt][j] + b2v[nt], 0.f) * w3v[nt];
            s += __shfl_xor(s, 1);
            s += __shfl_xor(s, 2);
            s += __shfl_xor(s, 4);
            s += __shfl_xor(s, 8);
            if (lc == 0) partl[w][16 * mt + 4 * lk + j] = s;
        }
    }
    __syncthreads();                               // B3: partl visible

    if (tid < 64) {
        float s = partl[0][tid] + partl[1][tid] + partl[2][tid] + partl[3][tid] + b3[0];
        out[(size_t)b * 65 + 1 + tid] = s;
    } else if (tid == 64) {
        out[(size_t)b * 65] = 0.f;                 // add_zero column
    }
}

extern "C" void kernel_launch(void* const* d_in, const int* in_sizes, int n_in,
                              void* d_out, int out_size, void* d_ws, size_t ws_size,
                              hipStream_t stream) {
    const float* X  = (const float*)d_in[0];
    const float* W1 = (const float*)d_in[1];
    const float* b1 = (const float*)d_in[2];
    const float* W2 = (const float*)d_in[3];
    const float* b2 = (const float*)d_in[4];
    const float* W3 = (const float*)d_in[5];
    const float* b3 = (const float*)d_in[6];
    float* out = (float*)d_out;

    u16* w1t = (u16*)d_ws;             // 64 KB
    u16* w2t = w1t + 256 * 128;        // 128 KB

    prep_weights<<<384, 256, 0, stream>>>(W1, W2, w1t, w2t);
    fused_mlp<<<NB, 256, 0, stream>>>(X, b1, b2, W3, b3, w1t, w2t, out);
}

// Round 7
// 122.153 us; speedup vs baseline: 6.1668x; 1.6530x over previous
//
#include <hip/hip_runtime.h>
#include <hip/hip_bf16.h>

typedef unsigned short u16;
typedef unsigned int   u32;
typedef __attribute__((ext_vector_type(8))) short bf16x8;
typedef __attribute__((ext_vector_type(4))) float f32x4;

#define NB 8192

__device__ __forceinline__ u32 pack2bf(float a, float b) {
    __hip_bfloat162 h = __float22bfloat162_rn(make_float2(a, b));  // v_cvt_pk_bf16_f32
    return *reinterpret_cast<u32*>(&h);
}

__device__ __forceinline__ u16 f2bf(float x) {
    u32 u = __float_as_uint(x);
    u32 r = u + 0x7FFFu + ((u >> 16) & 1u);
    return (u16)(r >> 16);
}

// Fragment-linear weight layouts: for each (wave, tile, ks) the 1KB a wave's
// frag-load consumes, in lane*16B order. Frag f stores elems [f*512 .. f*512+512).
//   w1fr: f = (wv*4 + mt)*4 + ks   (64 frags)  elem(l,j): W1[d][c], d=32ks+8*(l>>4)+j, c=64wv+16mt+(l&15)
//   w2fr: f = (wv*4 + et)*8 + ks   (128 frags) elem(l,j): W2[c][e], c=32ks+8*(l>>4)+j, e=64wv+16et+(l&15)
__global__ __launch_bounds__(256) void prep_weights(
    const float* __restrict__ W1, const float* __restrict__ W2,
    u16* __restrict__ w1fr, u16* __restrict__ w2fr)
{
    int tid = blockIdx.x * 256 + threadIdx.x;
    if (tid < 32768) {
        const int f = tid >> 9, r = tid & 511, l = r >> 3, j = r & 7;
        const int wv = f >> 4, mt = (f >> 2) & 3, ks = f & 3;
        const int c = 64 * wv + 16 * mt + (l & 15);
        const int d = 32 * ks + 8 * (l >> 4) + j;
        w1fr[tid] = f2bf(W1[d * 256 + c]);
    } else {
        const int t2 = tid - 32768;
        if (t2 < 65536) {
            const int f = t2 >> 9, r = t2 & 511, l = r >> 3, j = r & 7;
            const int wv = f >> 5, et = (f >> 3) & 3, ks = f & 7;
            const int e = 64 * wv + 16 * et + (l & 15);
            const int c = 32 * ks + 8 * (l >> 4) + j;
            w2fr[t2] = f2bf(W2[c * 256 + e]);
        }
    }
}

// One block = one batch b: 64 nodes, 4 waves. 32KB LDS arena, disjoint-lifetime
// tenants: xt (16KB) -> h1s (32KB) -> partl (1KB). 4 blocks/CU.
// Weight frag loads are contiguous 1KB per wave-instruction (frag-linear layout).
__global__ __launch_bounds__(256, 4) void fused_mlp(
    const float* __restrict__ X,
    const float* __restrict__ b1, const float* __restrict__ b2,
    const float* __restrict__ W3, const float* __restrict__ b3,
    const u16* __restrict__ w1fr, const u16* __restrict__ w2fr,
    float* __restrict__ out)
{
    __shared__ u16 smem[64 * 256];    // 32 KB arena
    u16* xt   = smem;                 // bf16 XT[n][d], 16B-chunk XOR-swizzled by (n&15)
    u16* h1s  = smem;                 // bf16 h1[n][c], same swizzle
    float* partl = (float*)smem;      // [4][64]

    const int tid = threadIdx.x;
    const int w   = tid >> 6;
    const int l   = tid & 63;
    const int lc  = l & 15;
    const int lk  = l >> 4;
    const int b   = blockIdx.x;
    const float* Xb = X + (size_t)b * 8192;

    const u16* w1b = w1fr + w * 8192  + l * 8;   // per-wave frag base (elems)
    const u16* w2b = w2fr + w * 16384 + l * 8;

    // ---------- phase 0: X[b] (d-major) -> LDS XT[n][d] bf16 ----------
    #pragma unroll
    for (int it = 0; it < 4; ++it) {
        const int dc = w + 4 * it, d0 = dc << 3;
        float v[8];
        #pragma unroll
        for (int j = 0; j < 8; ++j) v[j] = Xb[(d0 + j) * 64 + l];   // coalesced per j
        u32 pk[4];
        #pragma unroll
        for (int j = 0; j < 4; ++j) pk[j] = pack2bf(v[2 * j], v[2 * j + 1]);
        *(uint4*)(xt + l * 128 + ((dc ^ lc) << 3)) = make_uint4(pk[0], pk[1], pk[2], pk[3]);
    }

    // hoist ks=0 A-frag loads above the barrier (contiguous 1KB each)
    bf16x8 afrN[4];
    #pragma unroll
    for (int mt = 0; mt < 4; ++mt)
        afrN[mt] = *(const bf16x8*)(w1b + mt * 2048);
    __syncthreads();                               // B0: xt valid

    // ---------- layer 1: D1[c][n] = sum_d W1T[c][d] * XT[n][d] ----------
    f32x4 acc[4][4];
    #pragma unroll
    for (int mt = 0; mt < 4; ++mt)
        #pragma unroll
        for (int nt = 0; nt < 4; ++nt) acc[mt][nt] = (f32x4){0.f, 0.f, 0.f, 0.f};

    #pragma unroll
    for (int ks = 0; ks < 4; ++ks) {
        bf16x8 afr[4], bfr[4];
        #pragma unroll
        for (int mt = 0; mt < 4; ++mt) afr[mt] = afrN[mt];
        if (ks < 3) {                              // 1-deep prefetch, contiguous 1KB
            #pragma unroll
            for (int mt = 0; mt < 4; ++mt)
                afrN[mt] = *(const bf16x8*)(w1b + (mt * 4 + ks + 1) * 512);
        }
        #pragma unroll
        for (int nt = 0; nt < 4; ++nt)
            bfr[nt] = *(const bf16x8*)(xt + (16 * nt + lc) * 128 + (((4 * ks + lk) ^ lc) << 3));
        #pragma unroll
        for (int mt = 0; mt < 4; ++mt)
            #pragma unroll
            for (int nt = 0; nt < 4; ++nt)
                acc[mt][nt] = __builtin_amdgcn_mfma_f32_16x16x32_bf16(afr[mt], bfr[nt], acc[mt][nt], 0, 0, 0);
    }
    __syncthreads();                               // B1: xt readers done before h1 overwrite

    // ---------- epilogue 1: +b1, relu, bf16 -> h1s ----------
    #pragma unroll
    for (int mt = 0; mt < 4; ++mt) {
        const int c0 = 64 * w + 16 * mt + 4 * lk;
        const float4 bv = *(const float4*)(b1 + c0);
        #pragma unroll
        for (int nt = 0; nt < 4; ++nt) {
            const int n = 16 * nt + lc;
            float x0 = fmaxf(acc[mt][nt][0] + bv.x, 0.f);
            float x1 = fmaxf(acc[mt][nt][1] + bv.y, 0.f);
            float x2 = fmaxf(acc[mt][nt][2] + bv.z, 0.f);
            float x3 = fmaxf(acc[mt][nt][3] + bv.w, 0.f);
            const int chunk = (c0 >> 3) ^ lc;
            *(uint2*)(h1s + n * 256 + (chunk << 3) + (c0 & 7)) =
                make_uint2(pack2bf(x0, x1), pack2bf(x2, x3));
        }
    }

    // hoist ks=0 B-frag loads above the barrier
    bf16x8 bfrN[4];
    #pragma unroll
    for (int nt = 0; nt < 4; ++nt)
        bfrN[nt] = *(const bf16x8*)(w2b + nt * 4096);
    __syncthreads();                               // B2: h1s visible

    // ---------- layer 2: D2[n][e] = sum_c h1[n][c] * W2T[e][c] ----------
    f32x4 acc2[4][4];
    #pragma unroll
    for (int mt = 0; mt < 4; ++mt)
        #pragma unroll
        for (int nt = 0; nt < 4; ++nt) acc2[mt][nt] = (f32x4){0.f, 0.f, 0.f, 0.f};

    #pragma unroll
    for (int ks = 0; ks < 8; ++ks) {
        bf16x8 afr[4], bfr[4];
        #pragma unroll
        for (int nt = 0; nt < 4; ++nt) bfr[nt] = bfrN[nt];
        if (ks < 7) {
            #pragma unroll
            for (int nt = 0; nt < 4; ++nt)
                bfrN[nt] = *(const bf16x8*)(w2b + (nt * 8 + ks + 1) * 512);
        }
        #pragma unroll
        for (int mt = 0; mt < 4; ++mt)
            afr[mt] = *(const bf16x8*)(h1s + (16 * mt + lc) * 256 + (((4 * ks + lk) ^ lc) << 3));
        #pragma unroll
        for (int mt = 0; mt < 4; ++mt)
            #pragma unroll
            for (int nt = 0; nt < 4; ++nt)
                acc2[mt][nt] = __builtin_amdgcn_mfma_f32_16x16x32_bf16(afr[mt], bfr[nt], acc2[mt][nt], 0, 0, 0);
    }
    __syncthreads();                               // B3: h1s readers done, partl may overwrite

    // ---------- layer 3: +b2, relu, dot W3, reduce over e ----------
    float b2v[4], w3v[4];
    #pragma unroll
    for (int nt = 0; nt < 4; ++nt) {
        const int e = 64 * w + 16 * nt + lc;
        b2v[nt] = b2[e];
        w3v[nt] = W3[e];
    }
    #pragma unroll
    for (int mt = 0; mt < 4; ++mt) {
        #pragma unroll
        for (int j = 0; j < 4; ++j) {              // row n = 16mt + 4lk + j
            float s = 0.f;
            #pragma unroll
            for (int nt = 0; nt < 4; ++nt)
                s += fmaxf(acc2[mt][nt][j] + b2v[nt], 0.f) * w3v[nt];
            s += __shfl_xor(s, 1);
            s += __shfl_xor(s, 2);
            s += __shfl_xor(s, 4);
            s += __shfl_xor(s, 8);
            if (lc == 0) partl[w * 64 + 16 * mt + 4 * lk + j] = s;
        }
    }
    __syncthreads();                               // B4: partl visible

    if (tid < 64) {
        float s = partl[0 * 64 + tid] + partl[1 * 64 + tid] + partl[2 * 64 + tid] + partl[3 * 64 + tid] + b3[0];
        out[(size_t)b * 65 + 1 + tid] = s;
    } else if (tid == 64) {
        out[(size_t)b * 65] = 0.f;                 // add_zero column
    }
}

extern "C" void kernel_launch(void* const* d_in, const int* in_sizes, int n_in,
                              void* d_out, int out_size, void* d_ws, size_t ws_size,
                              hipStream_t stream) {
    const float* X  = (const float*)d_in[0];
    const float* W1 = (const float*)d_in[1];
    const float* b1 = (const float*)d_in[2];
    const float* W2 = (const float*)d_in[3];
    const float* b2 = (const float*)d_in[4];
    const float* W3 = (const float*)d_in[5];
    const float* b3 = (const float*)d_in[6];
    float* out = (float*)d_out;

    u16* w1fr = (u16*)d_ws;            // 32768 elems = 64 KB
    u16* w2fr = w1fr + 32768;          // 65536 elems = 128 KB

    prep_weights<<<384, 256, 0, stream>>>(W1, W2, w1fr, w2fr);
    fused_mlp<<<NB, 256, 0, stream>>>(X, b1, b2, W3, b3, w1fr, w2fr, out);
}